// Round 14
// baseline (52.498 us; speedup 1.0000x reference)
//
#include <hip/hip_runtime.h>
#include <hip/hip_bf16.h>

typedef __attribute__((ext_vector_type(8))) short short8;
typedef __attribute__((ext_vector_type(4))) short s16x4;
typedef __attribute__((ext_vector_type(4))) float f32x4;

#define NB_H 96
#define NB_W 128
#define NB_D 32
#define NB_C 16
#define NB_F 16
#define NPIX (2 * NB_H * NB_W)                 // 24576
#define KB2_U16 (14 * 512)                     // 7168 u16 = 14336 B
#define WS_NEED ((size_t)KB2_U16 * 2)
#define SLAB_STRIDE 1280                       // 32 rows * 40 B (32 data + 8 pad)
#define NSLAB 18                               // 3h x 6w (4-px row tile + halo)
#define DV_OFF (NSLAB * SLAB_STRIDE)           // 23040
#define LDS_BYTES (DV_OFF + 64)                // 23104

// fp32 -> bf16 RNE
static __device__ __forceinline__ short fcvt(float f) {
  return (short)__builtin_bit_cast(unsigned short, __float2bfloat16(f));
}

// Pair table: p=3q+m (q=0..3): m=0 -> taps(6q,6q+1) [UNIF n=2q, kd=0/1];
// m=1 -> (6q+3,6q+4) [UNIF n=2q+1]; m=2 -> (6q+2,6q+5) [MIX kd=2].
// p=12 -> (24,25) [UNIF n=8]. p=13 -> (26,pad). tap t = n*3+kd.

// ---- weights prep: kern fp32 -> bf16 B-frag layout [p][grp][f][j] ---------
__global__ __launch_bounds__(256) void sconv3d_wprep(
    const float* __restrict__ kern, unsigned short* __restrict__ kb2) {
  const int i = blockIdx.x * 256 + threadIdx.x;
  if (i >= KB2_U16) return;
  const int p = i >> 9;
  const int g = (i >> 7) & 3;
  const int f = (i >> 3) & 15;
  const int j = i & 7;
  const int k = g * 8 + j;
  int lo, hi;
  if (p < 12) {
    const int q = p / 3, m = p % 3;
    lo = (m == 0) ? 6 * q : (m == 1) ? 6 * q + 3 : 6 * q + 2;
    hi = (m == 0) ? 6 * q + 1 : (m == 1) ? 6 * q + 4 : 6 * q + 5;
  } else if (p == 12) { lo = 24; hi = 25; }
  else { lo = 26; hi = -1; }
  const int t = (k < 16) ? lo : hi;
  const int c = k & 15;
  kb2[i] = (t >= 0) ? (unsigned short)fcvt(kern[(t * 16 + c) * 16 + f])
                    : (unsigned short)0;
}

// ---- main: 4-px row tile, 512 thr, wave = one d-tile of one pixel ---------
__global__ __launch_bounds__(512, 2) void sconv3d_fused6(
    const float* __restrict__ img, const int* __restrict__ bp,
    const unsigned short* __restrict__ kb2, const float* __restrict__ dvp,
    float* __restrict__ out) {
  __shared__ char Sb[LDS_BYTES];
  const int tid = threadIdx.x;
  const int lane = tid & 63;
  const int r = lane & 15;          // A: d row (low); B/D: f column
  const int grp = lane >> 4;        // 0..3
  const int vc = (grp & 1) * 16;    // byte offset of c-slice within 32B row
  const int halfbit = grp >> 1;     // K half: 0 -> tap lo, 1 -> tap hi
  const int voff_dv = DV_OFF + vc;

  // wave identity: pixel + d-tile
  const int wid = __builtin_amdgcn_readfirstlane((int)(tid >> 6));  // 0..7
  const int px_i = wid >> 1;        // 0..3
  const int tbase = (wid & 1) * 16; // d-tile base row
  const int rU = r + halfbit - 1 + tbase;  // UNIF row pre-rel
  const int rM = r + 1 + tbase;            // MIX row pre-rel

  // B-frags in registers (pinned after staging)
  short8 bfrag[14];
#pragma unroll
  for (int p = 0; p < 14; ++p)
    bfrag[p] = *(const short8*)(kb2 + p * 512 + grp * 128 + r * 8);

  // tile decode, XCD-chunked bijective swizzle: 6144 = 8 * 768
  const int bid = (blockIdx.x & 7) * 768 + (blockIdx.x >> 3);
  const int b = bid >= 3072;                  // 3072 tiles per batch
  const int rem = bid - b * 3072;
  const int h = rem >> 5;                     // 96 rows
  const int w0 = (rem & 31) * 4;              // 32 w-tiles

  // ---- staging: group g stages slabs {4g..4g+3} (+16+g for g<2) ----
  const int g = __builtin_amdgcn_readfirstlane((int)(tid >> 7));  // 0..3
  const int t2 = tid & 127;
  const int drow = t2 >> 2;                   // d row 0..31
  const int sq8 = (t2 & 3) * 8;               // byte offset in 32B row

  float4 stv[5];
  int soff[5];
#pragma unroll
  for (int k = 0; k < 5; ++k) {
    if (k < 4 || g < 2) {
      const int s = (k < 4) ? (g * 4 + k) : (16 + g);
      const int dh = s / 6, dw = s - 6 * dh;
      const int hh = min(max(h + dh - 1, 0), NB_H - 1);
      const int ww = min(max(w0 + dw - 1, 0), NB_W - 1);
      stv[k] = *(const float4*)(
          img + ((b * NB_H + hh) * NB_W + ww) * (NB_D * NB_C) + t2 * 4);
      soff[k] = s * SLAB_STRIDE + drow * 40 + sq8;
    }
  }

  // ---- pixel decode (fully scalar; overlaps staging load latency) ----
  const int w = w0 + px_i;
  const int pix = (b * NB_H + h) * NB_W + w;
  const int bpc = bp[pix];

#define CALCN(DI, DJ, SV, BA, RE)                                       \
  {                                                                     \
    const int hh = h + (DI), ww = w + (DJ);                             \
    SV = (hh >= 0) & (hh < NB_H) & (ww >= 0) & (ww < NB_W);             \
    const int hc = min(max(hh, 0), NB_H - 1);                           \
    const int wc = min(max(ww, 0), NB_W - 1);                           \
    RE = bpc - bp[(b * NB_H + hc) * NB_W + wc];                         \
    BA = (((DI) + 1) * 6 + px_i + (DJ) + 1) * SLAB_STRIDE;              \
  }

  int sv0, ba0, re0, sv1, ba1, re1, sv2, ba2, re2, sv3, ba3, re3;
  int sv4, ba4, re4, sv5, ba5, re5, sv6, ba6, re6, sv7, ba7, re7;
  int sv8, ba8, re8;
  CALCN(-1, -1, sv0, ba0, re0);
  CALCN(-1, 0, sv1, ba1, re1);
  CALCN(-1, 1, sv2, ba2, re2);
  CALCN(0, -1, sv3, ba3, re3);
  CALCN(0, 0, sv4, ba4, re4);
  CALCN(0, 1, sv5, ba5, re5);
  CALCN(1, -1, sv6, ba6, re6);
  CALCN(1, 0, sv7, ba7, re7);
  CALCN(1, 1, sv8, ba8, re8);
#undef CALCN

  // ---- drain staging loads: cvt + LDS write ----
#pragma unroll
  for (int k = 0; k < 5; ++k) {
    if (k < 4 || g < 2) {
      s16x4 o;
      o[0] = fcvt(stv[k].x); o[1] = fcvt(stv[k].y);
      o[2] = fcvt(stv[k].z); o[3] = fcvt(stv[k].w);
      *(s16x4*)(Sb + soff[k]) = o;
    }
  }
  if (tid < 16) ((unsigned short*)(Sb + DV_OFF))[tid] =
      (unsigned short)fcvt(dvp[0]);

#pragma unroll
  for (int p = 0; p < 14; ++p)
    asm volatile("" : "+v"(bfrag[p]));

  __syncthreads();

  // ---- compute: 14 pairs, one d-tile, 3-slot read pipeline ----
  f32x4 acc = {0.f, 0.f, 0.f, 0.f};
  short8 X, Y, Z;

#define LD(SREG, SV, BA, RE, RB)                                        \
  {                                                                     \
    const int d_ = (RB) + (RE);                                         \
    int o_ = (BA) + d_ * 40 + vc;                                       \
    o_ = ((SV) && (unsigned)d_ < NB_D) ? o_ : voff_dv;                  \
    SREG = *(const short8*)(Sb + o_);                                   \
  }

#define LD_U(SREG, N) LD(SREG, sv##N, ba##N, re##N, rU)

#define LD_M(SREG, NE, NO)                                              \
  {                                                                     \
    const int sv_ = halfbit ? sv##NO : sv##NE;                          \
    const int ba_ = halfbit ? ba##NO : ba##NE;                          \
    const int re_ = halfbit ? re##NO : re##NE;                          \
    LD(SREG, sv_, ba_, re_, rM)                                         \
  }

#define LD_M13(SREG, NE)                                                \
  {                                                                     \
    const int sv_ = halfbit ? 0 : sv##NE;                               \
    LD(SREG, sv_, ba##NE, re##NE, rM)                                   \
  }

#define FMA1(P, SREG)                                                   \
  acc = __builtin_amdgcn_mfma_f32_16x16x32_bf16(SREG, bfrag[P], acc, 0, 0, 0);

  LD_U(X, 0);                      // p0
  LD_U(Y, 1);                      // p1
  LD_M(Z, 0, 1);                   // p2
  FMA1(0, X);  LD_U(X, 2);         // p3
  FMA1(1, Y);  LD_U(Y, 3);         // p4
  FMA1(2, Z);  LD_M(Z, 2, 3);      // p5
  FMA1(3, X);  LD_U(X, 4);         // p6
  FMA1(4, Y);  LD_U(Y, 5);         // p7
  FMA1(5, Z);  LD_M(Z, 4, 5);      // p8
  FMA1(6, X);  LD_U(X, 6);         // p9
  FMA1(7, Y);  LD_U(Y, 7);         // p10
  FMA1(8, Z);  LD_M(Z, 6, 7);      // p11
  FMA1(9, X);  LD_U(X, 8);         // p12
  FMA1(10, Y); LD_M13(Y, 8);       // p13
  FMA1(11, Z);
  FMA1(12, X);
  FMA1(13, Y);

#undef LD
#undef LD_U
#undef LD_M
#undef LD_M13
#undef FMA1

  // D layout: col = lane&15 (=f), row = grp*4 + reg (+ tbase)
  const int obase = pix * (NB_D * NB_F) + tbase * NB_F;
#pragma unroll
  for (int rr = 0; rr < 4; ++rr)
    out[obase + (grp * 4 + rr) * NB_F + r] = acc[rr];
}

// ---------------- fallback (self-contained) if ws is too small -------------
__global__ __launch_bounds__(256) void sconv3d_mfma(
    const float* __restrict__ img, const int* __restrict__ bp,
    const float* __restrict__ kern, const float* __restrict__ dvp,
    float* __restrict__ out, int npix) {
  __shared__ unsigned short Kb[28 * 256];
  const int tid = threadIdx.x;
  for (int idx = tid; idx < 28 * 256; idx += 256) {
    unsigned short v = 0;
    if (idx < 27 * 256) v = (unsigned short)fcvt(kern[idx]);
    Kb[idx] = v;
  }
  __syncthreads();

  const int lane = tid & 63;
  const int grp = lane >> 4;
  const int r = lane & 15;
  const int c0 = (grp & 1) * 8;
  const int half = grp >> 1;

  short8 bfrag[14];
#pragma unroll
  for (int p = 0; p < 14; ++p) {
#pragma unroll
    for (int j = 0; j < 8; ++j) {
      const int k = 8 * grp + j;
      const int t = 2 * p + (k >> 4);
      bfrag[p][j] = (short)Kb[t * 256 + (k & 15) * 16 + r];
    }
  }

  const int pix = blockIdx.x * 4 + (tid >> 6);
  if (pix >= npix) return;
  const int b = pix / (NB_H * NB_W);
  const int rem = pix - b * (NB_H * NB_W);
  const int h = rem >> 7;
  const int w = rem & (NB_W - 1);

  const float dv = dvp[0];
  const int bpc = bp[pix];

  f32x4 acc0 = {0.f, 0.f, 0.f, 0.f};
  f32x4 acc1 = {0.f, 0.f, 0.f, 0.f};

#pragma unroll
  for (int p = 0; p < 14; ++p) {
    const int t = 2 * p + half;
    const int n = t / 3;
    const int kd = t - 3 * n;
    const int i = n / 3;
    const int j = n - 3 * i;
    const int hh = h + i - 1;
    const int ww = w + j - 1;
    const bool sv =
        (t < 27) && (hh >= 0) && (hh < NB_H) && (ww >= 0) && (ww < NB_W);
    const int hc = min(max(hh, 0), NB_H - 1);
    const int wc = min(max(ww, 0), NB_W - 1);
    const int nidx = (b * NB_H + hc) * NB_W + wc;
    const int rel = bpc - bp[nidx];
    const int base = nidx * (NB_D * NB_C);
    const int dsh = (kd - 1) + rel;

    const int ds0 = r + dsh;
    short8 a0;
    {
      float va[8];
      if (sv && (ds0 >= 0) && (ds0 < NB_D)) {
        const float4* pp = (const float4*)(img + base + ds0 * NB_C + c0);
        const float4 x = pp[0];
        const float4 y = pp[1];
        va[0] = x.x; va[1] = x.y; va[2] = x.z; va[3] = x.w;
        va[4] = y.x; va[5] = y.y; va[6] = y.z; va[7] = y.w;
      } else {
#pragma unroll
        for (int q = 0; q < 8; ++q) va[q] = dv;
      }
#pragma unroll
      for (int q = 0; q < 8; ++q) a0[q] = fcvt(va[q]);
    }
    acc0 = __builtin_amdgcn_mfma_f32_16x16x32_bf16(a0, bfrag[p], acc0, 0, 0, 0);

    const int ds1 = ds0 + 16;
    short8 a1;
    {
      float va[8];
      if (sv && (ds1 >= 0) && (ds1 < NB_D)) {
        const float4* pp = (const float4*)(img + base + ds1 * NB_C + c0);
        const float4 x = pp[0];
        const float4 y = pp[1];
        va[0] = x.x; va[1] = x.y; va[2] = x.z; va[3] = x.w;
        va[4] = y.x; va[5] = y.y; va[6] = y.z; va[7] = y.w;
      } else {
#pragma unroll
        for (int q = 0; q < 8; ++q) va[q] = dv;
      }
#pragma unroll
      for (int q = 0; q < 8; ++q) a1[q] = fcvt(va[q]);
    }
    acc1 = __builtin_amdgcn_mfma_f32_16x16x32_bf16(a1, bfrag[p], acc1, 0, 0, 0);
  }

  const int obase = pix * (NB_D * NB_F);
#pragma unroll
  for (int rr = 0; rr < 4; ++rr) {
    out[obase + (grp * 4 + rr) * NB_F + r] = acc0[rr];
    out[obase + (grp * 4 + rr + 16) * NB_F + r] = acc1[rr];
  }
}

extern "C" void kernel_launch(void* const* d_in, const int* in_sizes, int n_in,
                              void* d_out, int out_size, void* d_ws, size_t ws_size,
                              hipStream_t stream) {
  const float* img = (const float*)d_in[0];
  const int* bp = (const int*)d_in[1];
  const float* kern = (const float*)d_in[2];
  const float* dvp = (const float*)d_in[3];
  float* out = (float*)d_out;

  if (ws_size >= WS_NEED) {
    unsigned short* kb2 = (unsigned short*)d_ws;
    sconv3d_wprep<<<28, 256, 0, stream>>>(kern, kb2);
    sconv3d_fused6<<<NPIX / 4, 512, 0, stream>>>(img, bp, kb2, dvp, out);
  } else {
    sconv3d_mfma<<<NPIX / 4, 256, 0, stream>>>(img, bp, kern, dvp, out, NPIX);
  }
}